// Round 1
// baseline (1120.953 us; speedup 1.0000x reference)
//
#include <hip/hip_runtime.h>
#include <hip/hip_bf16.h>
#include <math.h>

#define N 8192
#define D 128
#define KNN 10
#define EPSF 1e-10f
#define BR 64
#define BC 64
#define CSTR 164   // candidate row stride (164%32=4 -> spreads merge-read banks)

// ---------------- Kernel 1: squared row norms (both matrices) ----------------
__global__ void sqnorm_kernel(const float* __restrict__ xc,
                              const float* __restrict__ xr,
                              float* __restrict__ sqc,
                              float* __restrict__ sqr) {
  int wid  = (blockIdx.x * blockDim.x + threadIdx.x) >> 6;  // one wave per row
  int lane = threadIdx.x & 63;
  if (wid >= 2 * N) return;
  const float* x = (wid < N) ? xc : xr;
  int row = (wid < N) ? wid : wid - N;
  float2 v = *reinterpret_cast<const float2*>(x + (size_t)row * D + lane * 2);
  float s = v.x * v.x + v.y * v.y;
  #pragma unroll
  for (int off = 32; off; off >>= 1) s += __shfl_xor(s, off, 64);
  if (lane == 0) ((wid < N) ? sqc : sqr)[row] = s;
}

// ---------------- top-10-smallest insertion into sorted register list -------
__device__ __forceinline__ void insert10(float (&lst)[KNN], float v) {
  if (v < lst[KNN - 1]) {
    lst[KNN - 1] = v;
    #pragma unroll
    for (int q = KNN - 1; q > 0; --q) {   // one bubble pass restores order
      float lo = fminf(lst[q - 1], lst[q]);
      float hi = fmaxf(lst[q - 1], lst[q]);
      lst[q - 1] = lo; lst[q] = hi;
    }
  }
}

// ---------------- Kernel 2: fused distance + per-row top-10 ----------------
// grid = 256: bid>>7 selects matrix, bid&127 selects 64-row block.
__global__ __launch_bounds__(256) void knn_kernel(
    const float* __restrict__ xc, const float* __restrict__ xr,
    const float* __restrict__ sqc, const float* __restrict__ sqr,
    float* __restrict__ knnc, float* __restrict__ knnr) {
  __shared__ union SMu {
    struct { float A[BR * D]; float B[BC * D]; } t;   // 64 KB
    float cand[BR * CSTR];                            // 42 KB (reused post-compute)
  } sm;
  float4* A4 = reinterpret_cast<float4*>(sm.t.A);
  float4* B4 = reinterpret_cast<float4*>(sm.t.B);

  const int bid = blockIdx.x;
  const int mat = bid >> 7;
  const int rb  = bid & 127;
  const float* __restrict__ x   = mat ? xr : xc;
  const float* __restrict__ sqv = mat ? sqr : sqc;
  float* __restrict__ knn       = mat ? knnr : knnc;
  const int row0 = rb * BR;
  const int t  = threadIdx.x;
  const int tx = t & 15, ty = t >> 4;

  // Stage A tile once (rows fixed per block). XOR chunk-swizzle vs bank conflicts.
  #pragma unroll
  for (int it = 0; it < 8; ++it) {
    int idx = it * 256 + t;
    int r = idx >> 5, ch = idx & 31;
    float4 g = *reinterpret_cast<const float4*>(x + (size_t)(row0 + r) * D + ch * 4);
    A4[r * 32 + (ch ^ (r & 7))] = g;
  }

  float cand[4][KNN];
  #pragma unroll
  for (int i = 0; i < 4; ++i)
    #pragma unroll
    for (int q = 0; q < KNN; ++q) cand[i][q] = 3.4e38f;

  float sqa[4];
  #pragma unroll
  for (int i = 0; i < 4; ++i) sqa[i] = sqv[row0 + ty + 16 * i];

  for (int cb = 0; cb < N / BC; ++cb) {
    __syncthreads();   // protect previous B tile reads (and A store on iter 0)
    #pragma unroll
    for (int it = 0; it < 8; ++it) {
      int idx = it * 256 + t;
      int r = idx >> 5, ch = idx & 31;
      float4 g = *reinterpret_cast<const float4*>(x + (size_t)(cb * BC + r) * D + ch * 4);
      B4[r * 32 + (ch ^ (r & 7))] = g;
    }
    __syncthreads();

    float acc[4][4];
    #pragma unroll
    for (int i = 0; i < 4; ++i)
      #pragma unroll
      for (int j = 0; j < 4; ++j) acc[i][j] = 0.f;

    // rows ty+16i, cols tx+16j: (row&7)=ty&7 const per thread -> conflict-free b128
    #pragma unroll 4
    for (int ch = 0; ch < 32; ++ch) {
      const int csa = ch ^ (ty & 7);
      const int csb = ch ^ (tx & 7);
      float4 av[4], bv[4];
      #pragma unroll
      for (int i = 0; i < 4; ++i) av[i] = A4[(ty + 16 * i) * 32 + csa];
      #pragma unroll
      for (int j = 0; j < 4; ++j) bv[j] = B4[(tx + 16 * j) * 32 + csb];
      #pragma unroll
      for (int i = 0; i < 4; ++i)
        #pragma unroll
        for (int j = 0; j < 4; ++j)
          acc[i][j] += av[i].x * bv[j].x + av[i].y * bv[j].y +
                       av[i].z * bv[j].z + av[i].w * bv[j].w;
    }

    #pragma unroll
    for (int j = 0; j < 4; ++j) {
      const int gc = cb * BC + tx + 16 * j;
      const float sqb = sqv[gc];
      #pragma unroll
      for (int i = 0; i < 4; ++i) {
        const int gr = row0 + ty + 16 * i;
        float d2 = sqa[i] + sqb - 2.f * acc[i][j];
        if (gc != gr) insert10(cand[i], d2);   // exclude self == drop sorted col 0
      }
    }
  }

  // Merge: 16 threads x 10 candidates per row -> global top-10 per row.
  __syncthreads();
  #pragma unroll
  for (int i = 0; i < 4; ++i) {
    int r = ty + 16 * i;
    #pragma unroll
    for (int q = 0; q < KNN; ++q)
      sm.cand[r * CSTR + tx * KNN + q] = cand[i][q];
  }
  __syncthreads();
  if (t < BR) {
    float best[KNN];
    #pragma unroll
    for (int q = 0; q < KNN; ++q) best[q] = 3.4e38f;
    for (int c = 0; c < 16 * KNN; ++c) insert10(best, sm.cand[t * CSTR + c]);
    #pragma unroll
    for (int q = 0; q < KNN; ++q)
      knn[(size_t)(row0 + t) * KNN + q] = sqrtf(fmaxf(best[q], 1e-12f));
  }
}

// ---------------- Kernel 3: per-sample Sinkhorn (one thread per sample) -----
__global__ void sinkhorn_kernel(const float* __restrict__ knnc,
                                const float* __restrict__ knnr,
                                float* __restrict__ ps) {
  int s = blockIdx.x * blockDim.x + threadIdx.x;
  if (s >= N) return;
  float a[KNN], b[KNN];
  float suma = 0.f, sumb = 0.f;
  #pragma unroll
  for (int q = 0; q < KNN; ++q) { a[q] = knnc[(size_t)s * KNN + q]; suma += a[q]; }
  #pragma unroll
  for (int q = 0; q < KNN; ++q) { b[q] = knnr[(size_t)s * KNN + q]; sumb += b[q]; }
  #pragma unroll
  for (int q = 0; q < KNN; ++q) { a[q] /= (suma + EPSF); b[q] /= (sumb + EPSF); }

  // K[i][j] = exp(-|i-j|) ; all Kp indices compile-time after unroll (rule #20)
  float Kp[KNN];
  Kp[0] = 1.f;
  const float e1 = 0.36787944117144233f;  // exp(-1)
  #pragma unroll
  for (int tt = 1; tt < KNN; ++tt) Kp[tt] = Kp[tt - 1] * e1;

  float u[KNN], v[KNN];
  #pragma unroll
  for (int q = 0; q < KNN; ++q) u[q] = 1.f;

  #pragma unroll 1
  for (int it = 0; it < 50; ++it) {
    #pragma unroll
    for (int j = 0; j < KNN; ++j) {
      float den = EPSF;
      #pragma unroll
      for (int i = 0; i < KNN; ++i) den += u[i] * Kp[i > j ? i - j : j - i];
      v[j] = b[j] / den;
    }
    #pragma unroll
    for (int i = 0; i < KNN; ++i) {
      float den = EPSF;
      #pragma unroll
      for (int j = 0; j < KNN; ++j) den += v[j] * Kp[i > j ? i - j : j - i];
      u[i] = a[i] / den;
    }
  }
  #pragma unroll
  for (int j = 0; j < KNN; ++j) {
    float den = EPSF;
    #pragma unroll
    for (int i = 0; i < KNN; ++i) den += u[i] * Kp[i > j ? i - j : j - i];
    v[j] = b[j] / den;
  }
  float cost = 0.f;
  #pragma unroll
  for (int i = 0; i < KNN; ++i) {
    float acc = 0.f;
    #pragma unroll
    for (int j = 0; j < KNN; ++j) {
      const int dd = i > j ? i - j : j - i;
      acc += Kp[dd] * ((float)dd * 0.1f) * v[j];   // (K*M)[i][j], M=|i-j|/10
    }
    cost += u[i] * acc;
  }
  ps[s] = cost;
}

// ---------------- Kernel 4: mean reduce -> scalar ----------------
__global__ void reduce_kernel(const float* __restrict__ ps, float* __restrict__ out) {
  __shared__ float red[256];
  int tid = threadIdx.x;
  float s = 0.f;
  for (int i = tid; i < N; i += 256) s += ps[i];
  red[tid] = s;
  __syncthreads();
  #pragma unroll
  for (int off = 128; off > 0; off >>= 1) {
    if (tid < off) red[tid] += red[tid + off];
    __syncthreads();
  }
  if (tid == 0) out[0] = red[0] * (1.0f / N);
}

extern "C" void kernel_launch(void* const* d_in, const int* in_sizes, int n_in,
                              void* d_out, int out_size, void* d_ws, size_t ws_size,
                              hipStream_t stream) {
  const float* xc = (const float*)d_in[0];   // embeddings
  const float* xr = (const float*)d_in[1];   // reference_embeddings
  float* out = (float*)d_out;
  float* ws  = (float*)d_ws;
  float* sqc  = ws;                          // N
  float* sqr  = sqc + N;                     // N
  float* knnc = sqr + N;                     // N*10
  float* knnr = knnc + (size_t)N * KNN;      // N*10
  float* ps   = knnr + (size_t)N * KNN;      // N

  sqnorm_kernel<<<dim3((2 * N) / 4), dim3(256), 0, stream>>>(xc, xr, sqc, sqr);
  knn_kernel<<<dim3(256), dim3(256), 0, stream>>>(xc, xr, sqc, sqr, knnc, knnr);
  sinkhorn_kernel<<<dim3(N / 256), dim3(256), 0, stream>>>(knnc, knnr, ps);
  reduce_kernel<<<dim3(1), dim3(256), 0, stream>>>(ps, out);
}

// Round 2
// 252.488 us; speedup vs baseline: 4.4396x; 4.4396x over previous
//
#include <hip/hip_runtime.h>
#include <hip/hip_bf16.h>
#include <math.h>

#define N 8192
#define D 128
#define NELEM (N * D)
#define KNN 10
#define EPSF 1e-10f
#define CB 256      // cols (owned samples) per block
#define RT 64       // rows per tile
#define NSLICE 8
#define RH 1024     // rows per slice (NSLICE*RH == N)

typedef unsigned short ushort_t;
typedef short bf16x8 __attribute__((ext_vector_type(8)));
typedef float f32x4 __attribute__((ext_vector_type(4)));

// ---------------- insertion into ascending top-L list ----------------
template <int L>
__device__ __forceinline__ void insertL(float (&lst)[L], float v) {
  if (v < lst[L - 1]) {
    lst[L - 1] = v;
    #pragma unroll
    for (int q = L - 1; q > 0; --q) {
      float lo = fminf(lst[q - 1], lst[q]);
      float hi = fmaxf(lst[q - 1], lst[q]);
      lst[q - 1] = lo; lst[q] = hi;
    }
  }
}

// ---------------- Kernel 0: fp32 -> bf16 (RTNE) prepass ----------------
__global__ void tobf16_kernel(const float* __restrict__ xc,
                              const float* __restrict__ xr,
                              ushort_t* __restrict__ out) {
  size_t i = ((size_t)blockIdx.x * 256 + threadIdx.x) * 8;
  const float* src = (i < (size_t)NELEM) ? xc : xr;
  size_t off = (i < (size_t)NELEM) ? i : i - NELEM;
  float4 v0 = *reinterpret_cast<const float4*>(src + off);
  float4 v1 = *reinterpret_cast<const float4*>(src + off + 4);
  auto cvt = [](float f) -> unsigned int {
    unsigned int b = __float_as_uint(f);
    return (b + 0x7FFFu + ((b >> 16) & 1u)) >> 16;   // RTNE
  };
  uint4 p;
  p.x = cvt(v0.x) | (cvt(v0.y) << 16);
  p.y = cvt(v0.z) | (cvt(v0.w) << 16);
  p.z = cvt(v1.x) | (cvt(v1.y) << 16);
  p.w = cvt(v1.z) | (cvt(v1.w) << 16);
  *reinterpret_cast<uint4*>(out + i) = p;
}

// ---------------- Kernel 1: squared row norms (fp32 inputs) ----------------
__global__ void sqnorm_kernel(const float* __restrict__ xc,
                              const float* __restrict__ xr,
                              float* __restrict__ sq) {
  int wid  = (blockIdx.x * blockDim.x + threadIdx.x) >> 6;  // one wave per row
  int lane = threadIdx.x & 63;
  if (wid >= 2 * N) return;
  const float* x = (wid < N) ? xc : xr;
  int row = (wid < N) ? wid : wid - N;
  float2 v = *reinterpret_cast<const float2*>(x + (size_t)row * D + lane * 2);
  float s = v.x * v.x + v.y * v.y;
  #pragma unroll
  for (int off = 32; off; off >>= 1) s += __shfl_xor(s, off, 64);
  if (lane == 0) sq[wid] = s;
}

// ---------------- Kernel 2: MFMA distance + per-column top-k ----------------
// grid = 512: mat = bid>>8, colblk = (bid>>3)&31, slice = bid&7.
// Block owns CB=256 cols (wave w: 64 cols), iterates RH=1024 rows in RT=64 tiles.
// Selection key = 0.5*sq[row] - dot(row,col)  (monotone in d2 per column).
__global__ __launch_bounds__(256) void knn_mfma(
    const ushort_t* __restrict__ xbf,   // [2][N][D] bf16 bits
    const float* __restrict__ sq,       // [2][N]
    float* __restrict__ partial) {      // [2*N][NSLICE][KNN]
  __shared__ __align__(16) ushort_t Albuf[2][RT * D];   // 2 x 16KB
  __shared__ float sqbuf[2][RT];

  const int bid = blockIdx.x;
  const int mat = bid >> 8;
  const int colblk = (bid >> 3) & 31;
  const int slice = bid & 7;
  const ushort_t* __restrict__ X = xbf + (size_t)mat * NELEM;
  const float* __restrict__ SQ = sq + mat * N;
  const int r0 = slice * RH;
  const int t = threadIdx.x;
  const int w = t >> 6, l = t & 63;
  const int c0 = colblk * CB + w * 64;       // wave's column base

  // --- B fragments (owned cols, full K=128) fixed in registers ---
  bf16x8 bfr[4][4];
  #pragma unroll
  for (int j = 0; j < 4; ++j) {
    const ushort_t* p = X + (size_t)(c0 + j * 16 + (l & 15)) * D + (l >> 4) * 8;
    #pragma unroll
    for (int kk = 0; kk < 4; ++kk)
      bfr[j][kk] = *reinterpret_cast<const bf16x8*>(p + kk * 32);
  }

  float cand[4][11];
  #pragma unroll
  for (int j = 0; j < 4; ++j)
    #pragma unroll
    for (int q = 0; q < 11; ++q) cand[j][q] = 3.4e38f;

  // --- async stage of one 64-row A tile (XOR-swizzled via pre-swizzled src) ---
  auto stage = [&](int tt, int bb) {
    const ushort_t* rowg = X + (size_t)(r0 + tt * RT) * D;
    #pragma unroll
    for (int k2 = 0; k2 < 4; ++k2) {
      int s = w * 256 + k2 * 64 + l;          // 16B-slot index this lane fills
      int row = s >> 4, chslot = s & 15;
      int ch = (chslot & 8) | ((chslot & 7) ^ (row & 7));  // involution
      const ushort_t* g = rowg + row * D + ch * 8;
      ushort_t* dst = &Albuf[bb][(w * 256 + k2 * 64) * 8]; // wave-uniform base
      __builtin_amdgcn_global_load_lds(
          (const __attribute__((address_space(1))) void*)g,
          (__attribute__((address_space(3))) void*)dst, 16, 0, 0);
    }
    if (w == 0) {
      const float* gs = SQ + r0 + tt * RT + l;
      float* dsts = &sqbuf[bb][0];
      __builtin_amdgcn_global_load_lds(
          (const __attribute__((address_space(1))) void*)gs,
          (__attribute__((address_space(3))) void*)dsts, 4, 0, 0);
    }
  };

  stage(0, 0);
  asm volatile("s_waitcnt vmcnt(0)" ::: "memory");
  __syncthreads();

  for (int tt = 0; tt < RH / RT; ++tt) {
    const int cur = tt & 1;
    if (tt < RH / RT - 1) stage(tt + 1, cur ^ 1);   // async prefetch next tile

    // per-lane row norms (broadcast reads, conflict-free)
    f32x4 sqa[4];
    #pragma unroll
    for (int i = 0; i < 4; ++i)
      sqa[i] = *reinterpret_cast<const f32x4*>(&sqbuf[cur][i * 16 + (l >> 4) * 4]);

    f32x4 acc[4][4];
    #pragma unroll
    for (int i = 0; i < 4; ++i)
      #pragma unroll
      for (int j = 0; j < 4; ++j) acc[i][j] = (f32x4)0.f;

    #pragma unroll
    for (int kk = 0; kk < 4; ++kk) {
      const int ch = kk * 4 + (l >> 4);
      const int chs = (ch & 8) | ((ch & 7) ^ (l & 7));
      bf16x8 af[4];
      #pragma unroll
      for (int i = 0; i < 4; ++i) {
        const int row = i * 16 + (l & 15);
        af[i] = *reinterpret_cast<const bf16x8*>(&Albuf[cur][(row * 16 + chs) * 8]);
      }
      #pragma unroll
      for (int i = 0; i < 4; ++i)
        #pragma unroll
        for (int j = 0; j < 4; ++j)
          acc[i][j] = __builtin_amdgcn_mfma_f32_16x16x32_bf16(af[i], bfr[j][kk],
                                                              acc[i][j], 0, 0, 0);
    }

    // epilogue: key = 0.5*sq[row] - dot ; insert into per-column top-11
    #pragma unroll
    for (int j = 0; j < 4; ++j)
      #pragma unroll
      for (int i = 0; i < 4; ++i)
        #pragma unroll
        for (int r = 0; r < 4; ++r) {
          float key = fmaf(0.5f, sqa[i][r], -acc[i][j][r]);
          insertL<11>(cand[j], key);
        }

    asm volatile("s_waitcnt vmcnt(0)" ::: "memory");
    __syncthreads();
  }

  // --- merge the 4 lane-groups holding the same columns (xor 16, then 32) ---
  #pragma unroll
  for (int step = 16; step <= 32; step <<= 1)
    #pragma unroll
    for (int j = 0; j < 4; ++j)
      #pragma unroll
      for (int q = 0; q < 11; ++q) {
        float o = __shfl_xor(cand[j][q], step, 64);
        insertL<11>(cand[j], o);
      }

  // --- write slice-partial top-10 (drop the self == slice minimum) ---
  if (l < 16) {
    #pragma unroll
    for (int j = 0; j < 4; ++j) {
      const int c = c0 + j * 16 + l;
      const int selfin = (c >= r0 && c < r0 + RH) ? 1 : 0;
      float* dst = partial + ((size_t)(mat * N + c) * NSLICE + slice) * KNN;
      #pragma unroll
      for (int q = 0; q < KNN; ++q) dst[q] = cand[j][q + selfin];
    }
  }
}

// ---------------- Kernel 3: merge slices, back to distances ----------------
__global__ void merge_kernel(const float* __restrict__ partial,
                             const float* __restrict__ sq,
                             float* __restrict__ knn) {
  int idx = blockIdx.x * blockDim.x + threadIdx.x;   // [0, 2N)
  if (idx >= 2 * N) return;
  float best[KNN];
  #pragma unroll
  for (int q = 0; q < KNN; ++q) best[q] = 3.4e38f;
  const float* p = partial + (size_t)idx * NSLICE * KNN;
  for (int s = 0; s < NSLICE * KNN; ++s) insertL<KNN>(best, p[s]);
  const float sqc = sq[idx];
  #pragma unroll
  for (int q = 0; q < KNN; ++q) {
    float d2 = fmaf(2.f, best[q], sqc);
    knn[(size_t)idx * KNN + q] = sqrtf(fmaxf(d2, 1e-12f));
  }
}

// ---------------- Kernel 4: per-sample Sinkhorn ----------------
__global__ void sinkhorn_kernel(const float* __restrict__ knnc,
                                const float* __restrict__ knnr,
                                float* __restrict__ ps) {
  int s = blockIdx.x * blockDim.x + threadIdx.x;
  if (s >= N) return;
  float a[KNN], b[KNN];
  float suma = 0.f, sumb = 0.f;
  #pragma unroll
  for (int q = 0; q < KNN; ++q) { a[q] = knnc[(size_t)s * KNN + q]; suma += a[q]; }
  #pragma unroll
  for (int q = 0; q < KNN; ++q) { b[q] = knnr[(size_t)s * KNN + q]; sumb += b[q]; }
  #pragma unroll
  for (int q = 0; q < KNN; ++q) { a[q] /= (suma + EPSF); b[q] /= (sumb + EPSF); }

  float Kp[KNN];
  Kp[0] = 1.f;
  const float e1 = 0.36787944117144233f;  // exp(-1)
  #pragma unroll
  for (int tt = 1; tt < KNN; ++tt) Kp[tt] = Kp[tt - 1] * e1;

  float u[KNN], v[KNN];
  #pragma unroll
  for (int q = 0; q < KNN; ++q) u[q] = 1.f;

  #pragma unroll 1
  for (int it = 0; it < 50; ++it) {
    #pragma unroll
    for (int j = 0; j < KNN; ++j) {
      float den = EPSF;
      #pragma unroll
      for (int i = 0; i < KNN; ++i) den += u[i] * Kp[i > j ? i - j : j - i];
      v[j] = b[j] / den;
    }
    #pragma unroll
    for (int i = 0; i < KNN; ++i) {
      float den = EPSF;
      #pragma unroll
      for (int j = 0; j < KNN; ++j) den += v[j] * Kp[i > j ? i - j : j - i];
      u[i] = a[i] / den;
    }
  }
  #pragma unroll
  for (int j = 0; j < KNN; ++j) {
    float den = EPSF;
    #pragma unroll
    for (int i = 0; i < KNN; ++i) den += u[i] * Kp[i > j ? i - j : j - i];
    v[j] = b[j] / den;
  }
  float cost = 0.f;
  #pragma unroll
  for (int i = 0; i < KNN; ++i) {
    float acc = 0.f;
    #pragma unroll
    for (int j = 0; j < KNN; ++j) {
      const int dd = i > j ? i - j : j - i;
      acc += Kp[dd] * ((float)dd * 0.1f) * v[j];
    }
    cost += u[i] * acc;
  }
  ps[s] = cost;
}

// ---------------- Kernel 5: mean reduce ----------------
__global__ void reduce_kernel(const float* __restrict__ ps, float* __restrict__ out) {
  __shared__ float red[256];
  int tid = threadIdx.x;
  float s = 0.f;
  for (int i = tid; i < N; i += 256) s += ps[i];
  red[tid] = s;
  __syncthreads();
  #pragma unroll
  for (int off = 128; off > 0; off >>= 1) {
    if (tid < off) red[tid] += red[tid + off];
    __syncthreads();
  }
  if (tid == 0) out[0] = red[0] * (1.0f / N);
}

extern "C" void kernel_launch(void* const* d_in, const int* in_sizes, int n_in,
                              void* d_out, int out_size, void* d_ws, size_t ws_size,
                              hipStream_t stream) {
  const float* xc = (const float*)d_in[0];
  const float* xr = (const float*)d_in[1];
  float* out = (float*)d_out;
  float* ws = (float*)d_ws;

  float* sq = ws;                                   // 2N floats
  ushort_t* xbf = (ushort_t*)(ws + 2 * N);          // 2*N*D bf16 (4MB)
  float* partial = ws + 2 * N + NELEM;              // 2N*NSLICE*KNN floats
  float* knn = partial + (size_t)2 * N * NSLICE * KNN;  // 2N*KNN floats
  float* ps = knn + (size_t)2 * N * KNN;            // N floats

  tobf16_kernel<<<dim3(2 * NELEM / (256 * 8)), dim3(256), 0, stream>>>(xc, xr, xbf);
  sqnorm_kernel<<<dim3(2 * N / 4), dim3(256), 0, stream>>>(xc, xr, sq);
  knn_mfma<<<dim3(512), dim3(256), 0, stream>>>(xbf, sq, partial);
  merge_kernel<<<dim3((2 * N + 255) / 256), dim3(256), 0, stream>>>(partial, sq, knn);
  sinkhorn_kernel<<<dim3(N / 256), dim3(256), 0, stream>>>(knn, knn + (size_t)N * KNN, ps);
  reduce_kernel<<<dim3(1), dim3(256), 0, stream>>>(ps, out);
}

// Round 3
// 134.559 us; speedup vs baseline: 8.3306x; 1.8764x over previous
//
#include <hip/hip_runtime.h>
#include <hip/hip_bf16.h>
#include <math.h>

#define N 8192
#define D 128
#define NELEM (N * D)
#define KNN 10
#define EPSF 1e-10f
#define CB 256      // cols (owned samples) per block
#define RT 64       // rows per tile
#define NSLICE 8
#define RH 1024     // rows per slice (NSLICE*RH == N)

typedef unsigned short ushort_t;
typedef short bf16x8 __attribute__((ext_vector_type(8)));
typedef float f32x4 __attribute__((ext_vector_type(4)));

// ---- branchless sorted-insert: l ascending, keep smallest L ----
// med3(l[q-1], l[q], v) is the new q-th smallest; independent ops, idempotent
// when v >= l[L-1] -> no compare, no branch, no divergence cost.
template <int L>
__device__ __forceinline__ void insM(float (&l)[L], float v) {
  #pragma unroll
  for (int q = L - 1; q >= 1; --q)
    l[q] = __builtin_amdgcn_fmed3f(l[q - 1], l[q], v);
  l[0] = fminf(l[0], v);
}

// ---------------- Kernel 0: fused prep: bf16(x), bf16(-2x), sq ----------------
__global__ void prep_kernel(const float* __restrict__ xc,
                            const float* __restrict__ xr,
                            ushort_t* __restrict__ xb,    // [2][N][D] bf16(x)
                            ushort_t* __restrict__ xa,    // [2][N][D] bf16(-2x)
                            float* __restrict__ sq) {     // [2][N] fp32
  int wid  = (blockIdx.x * blockDim.x + threadIdx.x) >> 6;  // row in [0, 2N)
  int lane = threadIdx.x & 63;
  if (wid >= 2 * N) return;
  const float* x = (wid < N) ? xc : xr;
  int row = (wid < N) ? wid : wid - N;
  float2 v = *reinterpret_cast<const float2*>(x + (size_t)row * D + lane * 2);
  float s = v.x * v.x + v.y * v.y;
  #pragma unroll
  for (int off = 32; off; off >>= 1) s += __shfl_xor(s, off, 64);
  if (lane == 0) sq[wid] = s;
  auto cvt = [](float f) -> unsigned int {
    unsigned int b = __float_as_uint(f);
    return (b + 0x7FFFu + ((b >> 16) & 1u)) >> 16;   // RTNE
  };
  unsigned int pb = cvt(v.x) | (cvt(v.y) << 16);
  unsigned int pa = cvt(-2.f * v.x) | (cvt(-2.f * v.y) << 16);
  *reinterpret_cast<unsigned int*>(xb + (size_t)wid * D + lane * 2) = pb;
  *reinterpret_cast<unsigned int*>(xa + (size_t)wid * D + lane * 2) = pa;
}

// ---------------- Kernel 1: MFMA distance + per-column top-11 ----------------
// grid = 512: mat = bid>>8, colblk = (bid>>3)&31, slice = bid&7.
// A-operand = bf16(-2x) staged in LDS; C-init = sq[row]
// => acc directly holds key = sq_row - 2*dot  (d2 = key + sq_col).
__global__ __launch_bounds__(256) void knn_mfma(
    const ushort_t* __restrict__ xb,    // bf16(x)   [2][N][D]
    const ushort_t* __restrict__ xa,    // bf16(-2x) [2][N][D]
    const float* __restrict__ sq,       // [2][N]
    float* __restrict__ partial) {      // [2*N][NSLICE][KNN]
  __shared__ __align__(16) ushort_t Albuf[2][RT * D];   // 2 x 16KB
  __shared__ float sqbuf[2][RT];

  const int bid = blockIdx.x;
  const int mat = bid >> 8;
  const int colblk = (bid >> 3) & 31;
  const int slice = bid & 7;
  const ushort_t* __restrict__ XB = xb + (size_t)mat * NELEM;
  const ushort_t* __restrict__ XA = xa + (size_t)mat * NELEM;
  const float* __restrict__ SQ = sq + mat * N;
  const int r0 = slice * RH;
  const int t = threadIdx.x;
  const int w = t >> 6, l = t & 63;
  const int c0 = colblk * CB + w * 64;       // wave's column base

  // --- B fragments (owned cols, full K=128) fixed in registers ---
  bf16x8 bfr[4][4];
  #pragma unroll
  for (int j = 0; j < 4; ++j) {
    const ushort_t* p = XB + (size_t)(c0 + j * 16 + (l & 15)) * D + (l >> 4) * 8;
    #pragma unroll
    for (int kk = 0; kk < 4; ++kk)
      bfr[j][kk] = *reinterpret_cast<const bf16x8*>(p + kk * 32);
  }

  float cand[4][11];
  #pragma unroll
  for (int j = 0; j < 4; ++j)
    #pragma unroll
    for (int q = 0; q < 11; ++q) cand[j][q] = 3.4e38f;

  // --- async stage of one 64-row A tile (XOR-swizzled via pre-swizzled src) ---
  auto stage = [&](int tt, int bb) {
    const ushort_t* rowg = XA + (size_t)(r0 + tt * RT) * D;
    #pragma unroll
    for (int k2 = 0; k2 < 4; ++k2) {
      int s = w * 256 + k2 * 64 + l;          // 16B-slot index this lane fills
      int row = s >> 4, chslot = s & 15;
      int ch = (chslot & 8) | ((chslot & 7) ^ (row & 7));  // involution
      const ushort_t* g = rowg + row * D + ch * 8;
      ushort_t* dst = &Albuf[bb][(w * 256 + k2 * 64) * 8]; // wave-uniform base
      __builtin_amdgcn_global_load_lds(
          (const __attribute__((address_space(1))) void*)g,
          (__attribute__((address_space(3))) void*)dst, 16, 0, 0);
    }
    if (w == 0) {
      const float* gs = SQ + r0 + tt * RT + l;
      float* dsts = &sqbuf[bb][0];
      __builtin_amdgcn_global_load_lds(
          (const __attribute__((address_space(1))) void*)gs,
          (__attribute__((address_space(3))) void*)dsts, 4, 0, 0);
    }
  };

  stage(0, 0);
  asm volatile("s_waitcnt vmcnt(0)" ::: "memory");
  __syncthreads();

  for (int tt = 0; tt < RH / RT; ++tt) {
    const int cur = tt & 1;
    if (tt < RH / RT - 1) stage(tt + 1, cur ^ 1);   // async prefetch next tile

    // C-init: acc = sq[row]  (rows: i*16 + (l>>4)*4 + r)
    f32x4 sqi[4];
    #pragma unroll
    for (int i = 0; i < 4; ++i)
      sqi[i] = *reinterpret_cast<const f32x4*>(&sqbuf[cur][i * 16 + (l >> 4) * 4]);

    f32x4 acc[4][4];
    #pragma unroll
    for (int i = 0; i < 4; ++i)
      #pragma unroll
      for (int j = 0; j < 4; ++j) acc[i][j] = sqi[i];

    #pragma unroll
    for (int kk = 0; kk < 4; ++kk) {
      const int ch = kk * 4 + (l >> 4);
      const int chs = (ch & 8) | ((ch & 7) ^ (l & 7));
      bf16x8 af[4];
      #pragma unroll
      for (int i = 0; i < 4; ++i) {
        const int row = i * 16 + (l & 15);
        af[i] = *reinterpret_cast<const bf16x8*>(&Albuf[cur][(row * 16 + chs) * 8]);
      }
      #pragma unroll
      for (int i = 0; i < 4; ++i)
        #pragma unroll
        for (int j = 0; j < 4; ++j)
          acc[i][j] = __builtin_amdgcn_mfma_f32_16x16x32_bf16(af[i], bfr[j][kk],
                                                              acc[i][j], 0, 0, 0);
    }

    // branchless epilogue: 11 VALU ops/key, j-interleaved for ILP
    #pragma unroll
    for (int r = 0; r < 4; ++r)
      #pragma unroll
      for (int i = 0; i < 4; ++i)
        #pragma unroll
        for (int j = 0; j < 4; ++j)
          insM<11>(cand[j], acc[i][j][r]);

    asm volatile("s_waitcnt vmcnt(0)" ::: "memory");
    __syncthreads();
  }

  // --- merge the 4 lane-groups holding the same columns (xor 16, then 32) ---
  #pragma unroll
  for (int step = 16; step <= 32; step <<= 1)
    #pragma unroll
    for (int j = 0; j < 4; ++j)
      #pragma unroll
      for (int q = 0; q < 11; ++q) {
        float o = __shfl_xor(cand[j][q], step, 64);
        insM<11>(cand[j], o);
      }

  // --- write slice-partial top-10 (drop the self == slice minimum) ---
  if (l < 16) {
    #pragma unroll
    for (int j = 0; j < 4; ++j) {
      const int c = c0 + j * 16 + l;
      const int selfin = (c >= r0 && c < r0 + RH) ? 1 : 0;
      float* dst = partial + ((size_t)(mat * N + c) * NSLICE + slice) * KNN;
      #pragma unroll
      for (int q = 0; q < KNN; ++q) dst[q] = cand[j][q + selfin];
    }
  }
}

// ---------------- Kernel 2: merge slices, back to distances ----------------
__global__ void merge_kernel(const float* __restrict__ partial,
                             const float* __restrict__ sq,
                             float* __restrict__ knn) {
  int idx = blockIdx.x * blockDim.x + threadIdx.x;   // [0, 2N)
  if (idx >= 2 * N) return;
  float best[KNN];
  #pragma unroll
  for (int q = 0; q < KNN; ++q) best[q] = 3.4e38f;
  const float* p = partial + (size_t)idx * NSLICE * KNN;
  for (int s = 0; s < NSLICE * KNN; ++s) insM<KNN>(best, p[s]);
  const float sqc = sq[idx];
  #pragma unroll
  for (int q = 0; q < KNN; ++q) {
    float d2 = best[q] + sqc;                 // key + sq_col
    knn[(size_t)idx * KNN + q] = sqrtf(fmaxf(d2, 1e-12f));
  }
}

// ---------------- Kernel 3: per-sample Sinkhorn (Toeplitz scans + rcp) ------
// K[i][j] = e^{-|i-j|}: (K u)_j = L_j + e1*S_{j+1},
// L_j = u_j + e1*L_{j-1}, S_j = u_j + e1*S_{j+1}  -> 28 FMA per matvec.
__global__ void sinkhorn_kernel(const float* __restrict__ knnc,
                                const float* __restrict__ knnr,
                                float* __restrict__ ps) {
  int s = blockIdx.x * blockDim.x + threadIdx.x;
  if (s >= N) return;
  constexpr float E1 = 0.36787944117144233f;  // exp(-1)
  float a[KNN], b[KNN];
  float suma = 0.f, sumb = 0.f;
  #pragma unroll
  for (int q = 0; q < KNN; ++q) { a[q] = knnc[(size_t)s * KNN + q]; suma += a[q]; }
  #pragma unroll
  for (int q = 0; q < KNN; ++q) { b[q] = knnr[(size_t)s * KNN + q]; sumb += b[q]; }
  float rsa = __builtin_amdgcn_rcpf(suma + EPSF);
  float rsb = __builtin_amdgcn_rcpf(sumb + EPSF);
  #pragma unroll
  for (int q = 0; q < KNN; ++q) { a[q] *= rsa; b[q] *= rsb; }

  float u_[KNN], v_[KNN];
  #pragma unroll
  for (int q = 0; q < KNN; ++q) u_[q] = 1.f;

  #pragma unroll 1
  for (int it = 0; it < 50; ++it) {
    float L[KNN], S[KNN];
    L[0] = u_[0];
    #pragma unroll
    for (int q = 1; q < KNN; ++q) L[q] = fmaf(E1, L[q - 1], u_[q]);
    S[KNN - 1] = u_[KNN - 1];
    #pragma unroll
    for (int q = KNN - 2; q >= 0; --q) S[q] = fmaf(E1, S[q + 1], u_[q]);
    #pragma unroll
    for (int q = 0; q < KNN; ++q) {
      float den = (q < KNN - 1) ? fmaf(E1, S[q + 1], L[q]) : L[KNN - 1];
      v_[q] = b[q] * __builtin_amdgcn_rcpf(den + EPSF);
    }
    L[0] = v_[0];
    #pragma unroll
    for (int q = 1; q < KNN; ++q) L[q] = fmaf(E1, L[q - 1], v_[q]);
    S[KNN - 1] = v_[KNN - 1];
    #pragma unroll
    for (int q = KNN - 2; q >= 0; --q) S[q] = fmaf(E1, S[q + 1], v_[q]);
    #pragma unroll
    for (int q = 0; q < KNN; ++q) {
      float den = (q < KNN - 1) ? fmaf(E1, S[q + 1], L[q]) : L[KNN - 1];
      u_[q] = a[q] * __builtin_amdgcn_rcpf(den + EPSF);
    }
  }
  // final v = b / (K u + eps)
  {
    float L[KNN], S[KNN];
    L[0] = u_[0];
    #pragma unroll
    for (int q = 1; q < KNN; ++q) L[q] = fmaf(E1, L[q - 1], u_[q]);
    S[KNN - 1] = u_[KNN - 1];
    #pragma unroll
    for (int q = KNN - 2; q >= 0; --q) S[q] = fmaf(E1, S[q + 1], u_[q]);
    #pragma unroll
    for (int q = 0; q < KNN; ++q) {
      float den = (q < KNN - 1) ? fmaf(E1, S[q + 1], L[q]) : L[KNN - 1];
      v_[q] = b[q] * __builtin_amdgcn_rcpf(den + EPSF);
    }
  }
  // cost = sum_ij u_i * (K.M)[i][j] * v_j, weights compile-time constants
  float cost = 0.f;
  #pragma unroll
  for (int i = 0; i < KNN; ++i) {
    float accr = 0.f;
    #pragma unroll
    for (int j = 0; j < KNN; ++j) {
      const int dd = i > j ? i - j : j - i;
      const float w = 0.1f * (float)dd * __builtin_expf(-(float)dd); // folds
      accr = fmaf(w, v_[j], accr);
    }
    cost = fmaf(u_[i], accr, cost);
  }
  ps[s] = cost;
}

// ---------------- Kernel 4: mean reduce ----------------
__global__ void reduce_kernel(const float* __restrict__ ps, float* __restrict__ out) {
  __shared__ float red[256];
  int tid = threadIdx.x;
  float s = 0.f;
  for (int i = tid; i < N; i += 256) s += ps[i];
  red[tid] = s;
  __syncthreads();
  #pragma unroll
  for (int off = 128; off > 0; off >>= 1) {
    if (tid < off) red[tid] += red[tid + off];
    __syncthreads();
  }
  if (tid == 0) out[0] = red[0] * (1.0f / N);
}

extern "C" void kernel_launch(void* const* d_in, const int* in_sizes, int n_in,
                              void* d_out, int out_size, void* d_ws, size_t ws_size,
                              hipStream_t stream) {
  const float* xc = (const float*)d_in[0];
  const float* xr = (const float*)d_in[1];
  float* out = (float*)d_out;
  char* wsb = (char*)d_ws;

  float* sq       = (float*)wsb;                               // 2N f32 (64KB)
  ushort_t* xb    = (ushort_t*)(wsb + (1u << 16));             // 4MB
  ushort_t* xa    = (ushort_t*)(wsb + (1u << 16) + (4u << 20)); // 4MB
  float* partial  = (float*)(wsb + (1u << 16) + (8u << 20));   // 2N*80 f32 (5.24MB)
  float* knn      = partial + (size_t)2 * N * NSLICE * KNN;    // 2N*10 f32
  float* ps       = knn + (size_t)2 * N * KNN;                 // N f32

  prep_kernel<<<dim3(2 * N / 4), dim3(256), 0, stream>>>(xc, xr, xb, xa, sq);
  knn_mfma<<<dim3(512), dim3(256), 0, stream>>>(xb, xa, sq, partial);
  merge_kernel<<<dim3((2 * N + 255) / 256), dim3(256), 0, stream>>>(partial, sq, knn);
  sinkhorn_kernel<<<dim3(N / 64), dim3(64), 0, stream>>>(knn, knn + (size_t)N * KNN, ps);
  reduce_kernel<<<dim3(1), dim3(256), 0, stream>>>(ps, out);
}

// Round 4
// 110.615 us; speedup vs baseline: 10.1339x; 1.2165x over previous
//
#include <hip/hip_runtime.h>
#include <hip/hip_bf16.h>
#include <math.h>

#define N 8192
#define D 128
#define NELEM (N * D)
#define KNN 10
#define EPSF 1e-10f
#define RT 64       // rows per tile
#define NSLICE 8
#define RH 1024     // rows per slice (NSLICE*RH == N)
#define BIGF 3.0e38f

typedef unsigned short ushort_t;
typedef short bf16x8 __attribute__((ext_vector_type(8)));
typedef float f32x4 __attribute__((ext_vector_type(4)));

// ---- branchless sorted-insert: l ascending, keep smallest L ----
template <int L>
__device__ __forceinline__ void insM(float (&l)[L], float v) {
  #pragma unroll
  for (int q = L - 1; q >= 1; --q)
    l[q] = __builtin_amdgcn_fmed3f(l[q - 1], l[q], v);
  l[0] = fminf(l[0], v);
}

// ---------------- Kernel 0: fused prep: bf16(x), bf16(-2x), sq ----------------
__global__ void prep_kernel(const float* __restrict__ xc,
                            const float* __restrict__ xr,
                            ushort_t* __restrict__ xb,    // [2][N][D] bf16(x)
                            ushort_t* __restrict__ xa,    // [2][N][D] bf16(-2x)
                            float* __restrict__ sq) {     // [2][N] fp32
  int wid  = (blockIdx.x * blockDim.x + threadIdx.x) >> 6;  // row in [0, 2N)
  int lane = threadIdx.x & 63;
  if (wid >= 2 * N) return;
  const float* x = (wid < N) ? xc : xr;
  int row = (wid < N) ? wid : wid - N;
  float2 v = *reinterpret_cast<const float2*>(x + (size_t)row * D + lane * 2);
  float s = v.x * v.x + v.y * v.y;
  #pragma unroll
  for (int off = 32; off; off >>= 1) s += __shfl_xor(s, off, 64);
  if (lane == 0) sq[wid] = s;
  auto cvt = [](float f) -> unsigned int {
    unsigned int b = __float_as_uint(f);
    return (b + 0x7FFFu + ((b >> 16) & 1u)) >> 16;   // RTNE
  };
  unsigned int pb = cvt(v.x) | (cvt(v.y) << 16);
  unsigned int pa = cvt(-2.f * v.x) | (cvt(-2.f * v.y) << 16);
  *reinterpret_cast<unsigned int*>(xb + (size_t)wid * D + lane * 2) = pb;
  *reinterpret_cast<unsigned int*>(xa + (size_t)wid * D + lane * 2) = pa;
}

// ---------------- Kernel 1: MFMA distance + per-column top-10 ----------------
// grid = 1024: mat = bid>>9, colblk = (bid>>3)&63, slice = bid&7.
// Block: 4 waves x 32 cols = 128 cols, iterates RH=1024 rows in RT=64 tiles.
// A-operand = bf16(-2x) in LDS (XOR-swizzled); C-init = sq[row]
// => acc = key = sq_row - 2*dot  (d2 = key + sq_col). Self poisoned on diag tiles.
__global__ __launch_bounds__(256, 4) void knn_mfma(
    const ushort_t* __restrict__ xb,    // bf16(x)   [2][N][D]
    const ushort_t* __restrict__ xa,    // bf16(-2x) [2][N][D]
    const float* __restrict__ sq,       // [2][N]
    float* __restrict__ partial) {      // [2*N][NSLICE][KNN]
  __shared__ __align__(16) ushort_t Albuf[2][RT * D];   // 2 x 16KB
  __shared__ float sqbuf[2][RT];

  const int bid = blockIdx.x;
  const int mat = bid >> 9;
  const int colblk = (bid >> 3) & 63;
  const int slice = bid & 7;
  const ushort_t* __restrict__ XB = xb + (size_t)mat * NELEM;
  const ushort_t* __restrict__ XA = xa + (size_t)mat * NELEM;
  const float* __restrict__ SQ = sq + mat * N;
  const int r0 = slice * RH;
  const int t = threadIdx.x;
  const int w = t >> 6, l = t & 63;
  const int c0w = colblk * 128 + w * 32;     // wave's column base (32 cols)

  // --- B fragments (owned cols, full K=128) fixed in registers: 32 VGPR ---
  bf16x8 bfr[2][4];
  #pragma unroll
  for (int j = 0; j < 2; ++j) {
    const ushort_t* p = XB + (size_t)(c0w + j * 16 + (l & 15)) * D + (l >> 4) * 8;
    #pragma unroll
    for (int kk = 0; kk < 4; ++kk)
      bfr[j][kk] = *reinterpret_cast<const bf16x8*>(p + kk * 32);
  }

  float cand[2][KNN];
  #pragma unroll
  for (int j = 0; j < 2; ++j)
    #pragma unroll
    for (int q = 0; q < KNN; ++q) cand[j][q] = BIGF;

  // --- async stage of one 64-row A tile (XOR-swizzled via pre-swizzled src) ---
  auto stage = [&](int tt, int bb) {
    const ushort_t* rowg = XA + (size_t)(r0 + tt * RT) * D;
    #pragma unroll
    for (int k2 = 0; k2 < 4; ++k2) {
      int s = w * 256 + k2 * 64 + l;          // 16B-slot index this lane fills
      int row = s >> 4, chslot = s & 15;
      int ch = (chslot & 8) | ((chslot & 7) ^ (row & 7));  // involution
      const ushort_t* g = rowg + row * D + ch * 8;
      ushort_t* dst = &Albuf[bb][(w * 256 + k2 * 64) * 8]; // wave-uniform base
      __builtin_amdgcn_global_load_lds(
          (const __attribute__((address_space(1))) void*)g,
          (__attribute__((address_space(3))) void*)dst, 16, 0, 0);
    }
    if (w == 0) {
      const float* gs = SQ + r0 + tt * RT + l;
      float* dsts = &sqbuf[bb][0];
      __builtin_amdgcn_global_load_lds(
          (const __attribute__((address_space(1))) void*)gs,
          (__attribute__((address_space(3))) void*)dsts, 4, 0, 0);
    }
  };

  stage(0, 0);
  asm volatile("s_waitcnt vmcnt(0)" ::: "memory");
  __syncthreads();

  for (int tt = 0; tt < RH / RT; ++tt) {
    const int cur = tt & 1;
    if (tt < RH / RT - 1) stage(tt + 1, cur ^ 1);   // async prefetch next tile

    // C-init: acc = sq[row]  (rows: i*16 + (l>>4)*4 + r)
    f32x4 sqi[4];
    #pragma unroll
    for (int i = 0; i < 4; ++i)
      sqi[i] = *reinterpret_cast<const f32x4*>(&sqbuf[cur][i * 16 + (l >> 4) * 4]);

    f32x4 acc[4][2];
    #pragma unroll
    for (int i = 0; i < 4; ++i)
      #pragma unroll
      for (int j = 0; j < 2; ++j) acc[i][j] = sqi[i];

    #pragma unroll
    for (int kk = 0; kk < 4; ++kk) {
      const int ch = kk * 4 + (l >> 4);
      const int chs = (ch & 8) | ((ch & 7) ^ (l & 7));
      bf16x8 af[4];
      #pragma unroll
      for (int i = 0; i < 4; ++i) {
        const int row = i * 16 + (l & 15);
        af[i] = *reinterpret_cast<const bf16x8*>(&Albuf[cur][(row * 16 + chs) * 8]);
      }
      #pragma unroll
      for (int i = 0; i < 4; ++i)
        #pragma unroll
        for (int j = 0; j < 2; ++j)
          acc[i][j] = __builtin_amdgcn_mfma_f32_16x16x32_bf16(af[i], bfr[j][kk],
                                                              acc[i][j], 0, 0, 0);
    }

    // --- self-exclusion: poison row==col on (rare) diagonal tiles ---
    const int rbase = r0 + tt * RT;
    const unsigned diff = (unsigned)(c0w - rbase);
    if (diff < 64u) {                       // wave-uniform branch
      #pragma unroll
      for (int i = 0; i < 4; ++i)
        #pragma unroll
        for (int j = 0; j < 2; ++j) {
          const int rr = (int)diff + j * 16 + (l & 15) - i * 16 - ((l >> 4) << 2);
          #pragma unroll
          for (int r = 0; r < 4; ++r)
            if (rr == r) acc[i][j][r] = BIGF;   // cndmask after unroll
        }
    }

    // branchless epilogue: 10 VALU ops/key, j-interleaved for ILP
    #pragma unroll
    for (int r = 0; r < 4; ++r)
      #pragma unroll
      for (int i = 0; i < 4; ++i)
        #pragma unroll
        for (int j = 0; j < 2; ++j)
          insM<KNN>(cand[j], acc[i][j][r]);

    asm volatile("s_waitcnt vmcnt(0)" ::: "memory");
    __syncthreads();
  }

  // --- merge the 4 lane-groups holding the same columns (xor 16, then 32) ---
  #pragma unroll
  for (int step = 16; step <= 32; step <<= 1)
    #pragma unroll
    for (int j = 0; j < 2; ++j)
      #pragma unroll
      for (int q = 0; q < KNN; ++q) {
        float o = __shfl_xor(cand[j][q], step, 64);
        insM<KNN>(cand[j], o);
      }

  // --- write slice-partial top-10 ---
  if (l < 16) {
    #pragma unroll
    for (int j = 0; j < 2; ++j) {
      const int c = c0w + j * 16 + l;
      float* dst = partial + ((size_t)(mat * N + c) * NSLICE + slice) * KNN;
      #pragma unroll
      for (int q = 0; q < KNN; ++q) dst[q] = cand[j][q];
    }
  }
}

// ---------------- Kernel 2: merge slices, back to distances ----------------
__global__ void merge_kernel(const float* __restrict__ partial,
                             const float* __restrict__ sq,
                             float* __restrict__ knn) {
  int idx = blockIdx.x * blockDim.x + threadIdx.x;   // [0, 2N)
  if (idx >= 2 * N) return;
  float best[KNN];
  #pragma unroll
  for (int q = 0; q < KNN; ++q) best[q] = BIGF;
  const float* p = partial + (size_t)idx * NSLICE * KNN;
  for (int s = 0; s < NSLICE * KNN; ++s) insM<KNN>(best, p[s]);
  const float sqc = sq[idx];
  #pragma unroll
  for (int q = 0; q < KNN; ++q) {
    float d2 = best[q] + sqc;                 // key + sq_col
    knn[(size_t)idx * KNN + q] = sqrtf(fmaxf(d2, 1e-12f));
  }
}

// ---------------- Kernel 3: per-sample Sinkhorn (Toeplitz scans + rcp) ------
__global__ void sinkhorn_kernel(const float* __restrict__ knnc,
                                const float* __restrict__ knnr,
                                float* __restrict__ ps) {
  int s = blockIdx.x * blockDim.x + threadIdx.x;
  if (s >= N) return;
  constexpr float E1 = 0.36787944117144233f;  // exp(-1)
  float a[KNN], b[KNN];
  float suma = 0.f, sumb = 0.f;
  #pragma unroll
  for (int q = 0; q < KNN; ++q) { a[q] = knnc[(size_t)s * KNN + q]; suma += a[q]; }
  #pragma unroll
  for (int q = 0; q < KNN; ++q) { b[q] = knnr[(size_t)s * KNN + q]; sumb += b[q]; }
  float rsa = __builtin_amdgcn_rcpf(suma + EPSF);
  float rsb = __builtin_amdgcn_rcpf(sumb + EPSF);
  #pragma unroll
  for (int q = 0; q < KNN; ++q) { a[q] *= rsa; b[q] *= rsb; }

  float u_[KNN], v_[KNN];
  #pragma unroll
  for (int q = 0; q < KNN; ++q) u_[q] = 1.f;

  #pragma unroll 1
  for (int it = 0; it < 50; ++it) {
    float L[KNN], S[KNN];
    L[0] = u_[0];
    #pragma unroll
    for (int q = 1; q < KNN; ++q) L[q] = fmaf(E1, L[q - 1], u_[q]);
    S[KNN - 1] = u_[KNN - 1];
    #pragma unroll
    for (int q = KNN - 2; q >= 0; --q) S[q] = fmaf(E1, S[q + 1], u_[q]);
    #pragma unroll
    for (int q = 0; q < KNN; ++q) {
      float den = (q < KNN - 1) ? fmaf(E1, S[q + 1], L[q]) : L[KNN - 1];
      v_[q] = b[q] * __builtin_amdgcn_rcpf(den + EPSF);
    }
    L[0] = v_[0];
    #pragma unroll
    for (int q = 1; q < KNN; ++q) L[q] = fmaf(E1, L[q - 1], v_[q]);
    S[KNN - 1] = v_[KNN - 1];
    #pragma unroll
    for (int q = KNN - 2; q >= 0; --q) S[q] = fmaf(E1, S[q + 1], v_[q]);
    #pragma unroll
    for (int q = 0; q < KNN; ++q) {
      float den = (q < KNN - 1) ? fmaf(E1, S[q + 1], L[q]) : L[KNN - 1];
      u_[q] = a[q] * __builtin_amdgcn_rcpf(den + EPSF);
    }
  }
  {
    float L[KNN], S[KNN];
    L[0] = u_[0];
    #pragma unroll
    for (int q = 1; q < KNN; ++q) L[q] = fmaf(E1, L[q - 1], u_[q]);
    S[KNN - 1] = u_[KNN - 1];
    #pragma unroll
    for (int q = KNN - 2; q >= 0; --q) S[q] = fmaf(E1, S[q + 1], u_[q]);
    #pragma unroll
    for (int q = 0; q < KNN; ++q) {
      float den = (q < KNN - 1) ? fmaf(E1, S[q + 1], L[q]) : L[KNN - 1];
      v_[q] = b[q] * __builtin_amdgcn_rcpf(den + EPSF);
    }
  }
  float cost = 0.f;
  #pragma unroll
  for (int i = 0; i < KNN; ++i) {
    float accr = 0.f;
    #pragma unroll
    for (int j = 0; j < KNN; ++j) {
      const int dd = i > j ? i - j : j - i;
      const float wgt = 0.1f * (float)dd * __builtin_expf(-(float)dd); // folds
      accr = fmaf(wgt, v_[j], accr);
    }
    cost = fmaf(u_[i], accr, cost);
  }
  ps[s] = cost;
}

// ---------------- Kernel 4: mean reduce ----------------
__global__ void reduce_kernel(const float* __restrict__ ps, float* __restrict__ out) {
  __shared__ float red[256];
  int tid = threadIdx.x;
  float s = 0.f;
  for (int i = tid; i < N; i += 256) s += ps[i];
  red[tid] = s;
  __syncthreads();
  #pragma unroll
  for (int off = 128; off > 0; off >>= 1) {
    if (tid < off) red[tid] += red[tid + off];
    __syncthreads();
  }
  if (tid == 0) out[0] = red[0] * (1.0f / N);
}

extern "C" void kernel_launch(void* const* d_in, const int* in_sizes, int n_in,
                              void* d_out, int out_size, void* d_ws, size_t ws_size,
                              hipStream_t stream) {
  const float* xc = (const float*)d_in[0];
  const float* xr = (const float*)d_in[1];
  float* out = (float*)d_out;
  char* wsb = (char*)d_ws;

  float* sq       = (float*)wsb;                               // 2N f32 (64KB)
  ushort_t* xb    = (ushort_t*)(wsb + (1u << 16));             // 4MB
  ushort_t* xa    = (ushort_t*)(wsb + (1u << 16) + (4u << 20)); // 4MB
  float* partial  = (float*)(wsb + (1u << 16) + (8u << 20));   // 2N*80 f32 (5.24MB)
  float* knn      = partial + (size_t)2 * N * NSLICE * KNN;    // 2N*10 f32
  float* ps       = knn + (size_t)2 * N * KNN;                 // N f32

  prep_kernel<<<dim3(2 * N / 4), dim3(256), 0, stream>>>(xc, xr, xb, xa, sq);
  knn_mfma<<<dim3(1024), dim3(256), 0, stream>>>(xb, xa, sq, partial);
  merge_kernel<<<dim3((2 * N + 255) / 256), dim3(256), 0, stream>>>(partial, sq, knn);
  sinkhorn_kernel<<<dim3(N / 64), dim3(64), 0, stream>>>(knn, knn + (size_t)N * KNN, ps);
  reduce_kernel<<<dim3(1), dim3(256), 0, stream>>>(ps, out);
}